// Round 1
// baseline (118.006 us; speedup 1.0000x reference)
//
#include <hip/hip_runtime.h>
#include <hip/hip_bf16.h>

typedef __attribute__((ext_vector_type(8))) short short8;
typedef __attribute__((ext_vector_type(4))) float f32x4;
typedef __attribute__((ext_vector_type(2))) float f32x2;

#define M_TOTAL 131072
#define K_DIM 512
#define N_DIM 128
#define BM 128
#define BK 32
#define HALF 65536
#define MMD_BLOCKS 8192

__device__ __forceinline__ short bf16_bits(float f) {
    __hip_bfloat16 h = __float2bfloat16(f);
    return __builtin_bit_cast(short, h);
}

// ---------------- W -> W^T bf16 prep (one-time per call, 64K elems) ----------
__global__ void __launch_bounds__(256) wt_prep_kernel(
    const float* __restrict__ W, __hip_bfloat16* __restrict__ Wt)
{
    int idx = blockIdx.x * 256 + threadIdx.x;   // 65536 total
    int k = idx >> 7;        // 0..511
    int n = idx & 127;       // 0..127
    Wt[n * K_DIM + k] = __float2bfloat16(W[idx]);
}

// ---------------- GEMM: out = relu(x @ W + b), bf16 MFMA ---------------------
__global__ void __launch_bounds__(256) gemm_relu_kernel(
    const float* __restrict__ x, const __hip_bfloat16* __restrict__ Wt,
    const float* __restrict__ bias, float* __restrict__ out)
{
    __shared__ __hip_bfloat16 xa[BM][BK];     // 8 KB, x tile (bf16)
    __shared__ __hip_bfloat16 wb[N_DIM][BK];  // 8 KB, W^T tile (bf16)

    const int tid  = threadIdx.x;
    const int lane = tid & 63;
    const int wave = tid >> 6;          // 4 waves: 2x2 grid of 64x64 sub-tiles
    const int wrow = (wave & 1) * 64;
    const int wcol = (wave >> 1) * 64;
    const long row0 = (long)blockIdx.x * BM;

    f32x4 acc[4][4];
#pragma unroll
    for (int m = 0; m < 4; ++m)
#pragma unroll
        for (int n = 0; n < 4; ++n) acc[m][n] = (f32x4)(0.0f);

    const int sr = tid >> 2;            // x stage row 0..63
    const int sc = (tid & 3) * 8;       // x stage col {0,8,16,24}
    const int wn = tid >> 1;            // Wt stage row 0..127
    const int wk = (tid & 1) * 16;      // Wt stage k {0,16}

    for (int kt = 0; kt < K_DIM; kt += BK) {
        if (kt) __syncthreads();
        // stage x tile: f32 -> bf16
#pragma unroll
        for (int i = 0; i < 2; ++i) {
            const int rr = sr + i * 64;
            const float* src = x + (row0 + rr) * K_DIM + kt + sc;
            f32x4 f0 = *(const f32x4*)(src);
            f32x4 f1 = *(const f32x4*)(src + 4);
            short8 p;
            p[0] = bf16_bits(f0[0]); p[1] = bf16_bits(f0[1]);
            p[2] = bf16_bits(f0[2]); p[3] = bf16_bits(f0[3]);
            p[4] = bf16_bits(f1[0]); p[5] = bf16_bits(f1[1]);
            p[6] = bf16_bits(f1[2]); p[7] = bf16_bits(f1[3]);
            *(short8*)&xa[rr][sc] = p;
        }
        // stage W^T tile (already bf16)
        {
            const short8* src = (const short8*)(Wt + (long)wn * K_DIM + kt + wk);
            *(short8*)&wb[wn][wk]     = src[0];
            *(short8*)&wb[wn][wk + 8] = src[1];
        }
        __syncthreads();

        const int frow = lane & 15;
        const int kg   = (lane >> 4) * 8;
        short8 af[4], bfv[4];
#pragma unroll
        for (int m = 0; m < 4; ++m)
            af[m] = *(const short8*)&xa[wrow + m * 16 + frow][kg];
#pragma unroll
        for (int n = 0; n < 4; ++n)
            bfv[n] = *(const short8*)&wb[wcol + n * 16 + frow][kg];
#pragma unroll
        for (int m = 0; m < 4; ++m)
#pragma unroll
            for (int n = 0; n < 4; ++n)
                acc[m][n] = __builtin_amdgcn_mfma_f32_16x16x32_bf16(
                    af[m], bfv[n], acc[m][n], 0, 0, 0);
    }

    // epilogue: bias + relu + store (C/D layout: col=lane&15, row=(lane>>4)*4+reg)
    float bv[4];
#pragma unroll
    for (int n = 0; n < 4; ++n) bv[n] = bias[wcol + n * 16 + (lane & 15)];
    const int colb = wcol + (lane & 15);
    const long rowb = row0 + wrow + ((lane >> 4) * 4);
#pragma unroll
    for (int m = 0; m < 4; ++m)
#pragma unroll
        for (int j = 0; j < 4; ++j) {
            const long r = rowb + m * 16 + j;
            float* orow = out + r * N_DIM;
#pragma unroll
            for (int n = 0; n < 4; ++n) {
                float v = acc[m][n][j] + bv[n];
                orow[colb + n * 16] = fmaxf(v, 0.0f);
            }
        }
}

// ---------------- MMD: one wave per pair ------------------------------------
__device__ __forceinline__ float mk8(float D) {
    float s = 0.0f;
#pragma unroll
    for (int k = 0; k < 8; ++k) {
        const float invg = 16.0f / (float)(1 << k);  // 1/gamma_k, gamma_k=2^(k-4)
        s += expf(-D * invg);
    }
    return s * 0.125f;
}

__global__ void __launch_bounds__(256) mmd_partial_kernel(
    const float* __restrict__ out, double* __restrict__ partials)
{
    __shared__ float gs[4];
    const int tid  = threadIdx.x;
    const int lane = tid & 63;
    const int wv   = tid >> 6;
    const long p   = (long)blockIdx.x * 4 + wv;   // pair index, 32768 total

    const float* s0 = out + (2 * p) * N_DIM + 2 * lane;
    const float* s1 = s0 + N_DIM;
    const float* t0 = out + ((long)HALF + 2 * p) * N_DIM + 2 * lane;
    const float* t1 = t0 + N_DIM;

    f32x2 a0 = *(const f32x2*)s0;
    f32x2 a1 = *(const f32x2*)s1;
    f32x2 b0 = *(const f32x2*)t0;
    f32x2 b1 = *(const f32x2*)t1;

    float dss = (a0[0]-a1[0])*(a0[0]-a1[0]) + (a0[1]-a1[1])*(a0[1]-a1[1]);
    float dtt = (b0[0]-b1[0])*(b0[0]-b1[0]) + (b0[1]-b1[1])*(b0[1]-b1[1]);
    float dst = (a0[0]-b1[0])*(a0[0]-b1[0]) + (a0[1]-b1[1])*(a0[1]-b1[1]);
    float dts = (a1[0]-b0[0])*(a1[0]-b0[0]) + (a1[1]-b0[1])*(a1[1]-b0[1]);

#pragma unroll
    for (int off = 32; off; off >>= 1) {
        dss += __shfl_xor(dss, off, 64);
        dtt += __shfl_xor(dtt, off, 64);
        dst += __shfl_xor(dst, off, 64);
        dts += __shfl_xor(dts, off, 64);
    }

    float g = mk8(dss) + mk8(dtt) - mk8(dst) - mk8(dts);
    if (lane == 0) gs[wv] = g;
    __syncthreads();
    if (tid == 0)
        partials[blockIdx.x] = (double)gs[0] + (double)gs[1] +
                               (double)gs[2] + (double)gs[3];
}

__global__ void __launch_bounds__(256) mmd_reduce_kernel(
    const double* __restrict__ partials, float* __restrict__ loss)
{
    __shared__ double sd[256];
    const int tid = threadIdx.x;
    double s = 0.0;
    for (int i = tid; i < MMD_BLOCKS; i += 256) s += partials[i];
    sd[tid] = s;
    __syncthreads();
    for (int w = 128; w; w >>= 1) {
        if (tid < w) sd[tid] += sd[tid + w];
        __syncthreads();
    }
    if (tid == 0) loss[0] = (float)(sd[0] * (2.0 / 65536.0));
}

extern "C" void kernel_launch(void* const* d_in, const int* in_sizes, int n_in,
                              void* d_out, int out_size, void* d_ws, size_t ws_size,
                              hipStream_t stream) {
    const float* x = (const float*)d_in[0];
    const float* W = (const float*)d_in[1];
    const float* b = (const float*)d_in[2];
    float* out = (float*)d_out;                         // 131072*128 + 1 floats

    __hip_bfloat16* Wt = (__hip_bfloat16*)d_ws;                       // 128 KB
    double* partials = (double*)((char*)d_ws + 131072);               // 64 KB

    wt_prep_kernel<<<256, 256, 0, stream>>>(W, Wt);
    gemm_relu_kernel<<<1024, 256, 0, stream>>>(x, Wt, b, out);
    mmd_partial_kernel<<<MMD_BLOCKS, 256, 0, stream>>>(out, partials);
    mmd_reduce_kernel<<<1, 256, 0, stream>>>(partials,
                                             out + (long)M_TOTAL * N_DIM);
}